// Round 2
// baseline (2429.478 us; speedup 1.0000x reference)
//
#include <hip/hip_runtime.h>

#define NNODES 50000
#define NEDGES 1600000
#define IN_DIM 512
#define K1 1024
#define H1 2048
#define H2 2048
#define OUT_DIM 512
#define M_PAD 50048        // 391 * 128
#define TOTAL_TILES 391
#define CHUNK_TILES 49
#define CHUNK_M (CHUNK_TILES * 128)   // 6272 rows per MLP chunk

typedef unsigned short ushort_t;
typedef short sh8 __attribute__((ext_vector_type(8)));
typedef float f32x4 __attribute__((ext_vector_type(4)));

__device__ __forceinline__ ushort_t f2bf(float f) {
    unsigned u = __float_as_uint(f);
    unsigned r = (u + 0x7FFFu + ((u >> 16) & 1u)) >> 16;
    return (ushort_t)r;
}
__device__ __forceinline__ float bf2f(ushort_t h) {
    return __uint_as_float(((unsigned)h) << 16);
}

// ---------------- zero fill (replaces hipMemsetAsync) ----------------
__global__ void zero_kernel(int* __restrict__ p, int n) {
    int i = blockIdx.x * 256 + threadIdx.x;
    if (i < n) p[i] = 0;
}

// ---------------- x -> bf16 into h0[:, :512] ----------------
__global__ void convert_x_kernel(const float* __restrict__ x, ushort_t* __restrict__ h0) {
    int t = blockIdx.x * 256 + threadIdx.x;      // 50000*128 threads
    int n = t >> 7, c = t & 127;
    float4 v = ((const float4*)x)[n * 128 + c];
    ushort4 o;
    o.x = f2bf(v.x); o.y = f2bf(v.y); o.z = f2bf(v.z); o.w = f2bf(v.w);
    ((ushort4*)h0)[n * 256 + c] = o;
}

// ---------------- W (K x N fp32) -> Wt (N x K bf16) ----------------
__global__ void wtrans_kernel(const float* __restrict__ W, ushort_t* __restrict__ Wt,
                              int K, int Nn) {
    __shared__ float t[32][33];
    int n0 = blockIdx.x * 32, k0 = blockIdx.y * 32;
    int tx = threadIdx.x, ty = threadIdx.y;  // 32 x 8
#pragma unroll
    for (int i = 0; i < 4; i++)
        t[ty + 8 * i][tx] = W[(size_t)(k0 + ty + 8 * i) * Nn + n0 + tx];
    __syncthreads();
#pragma unroll
    for (int i = 0; i < 4; i++)
        Wt[(size_t)(n0 + ty + 8 * i) * K + k0 + tx] = f2bf(t[tx][ty + 8 * i]);
}

// ---------------- CSR build ----------------
__global__ void hist_kernel(const int* __restrict__ edst, int* __restrict__ counts) {
    int e = blockIdx.x * 256 + threadIdx.x;
    atomicAdd(&counts[edst[e]], 1);
}

__global__ void scan_kernel(const int* __restrict__ counts, int* __restrict__ offsets,
                            int* __restrict__ cursor, int n) {
    __shared__ int s[1024];
    __shared__ int carry_s;
    int tid = threadIdx.x;
    if (tid == 0) { carry_s = 0; offsets[0] = 0; }
    __syncthreads();
    for (int base = 0; base < n; base += 1024) {
        int i = base + tid;
        int c = (i < n) ? counts[i] : 0;
        s[tid] = c;
        __syncthreads();
        for (int off = 1; off < 1024; off <<= 1) {
            int v = (tid >= off) ? s[tid - off] : 0;
            __syncthreads();
            s[tid] += v;
            __syncthreads();
        }
        int carry = carry_s;
        if (i < n) {
            offsets[i + 1] = carry + s[tid];
            cursor[i] = carry + s[tid] - c;
        }
        __syncthreads();
        if (tid == 1023) carry_s = carry + s[1023];
        __syncthreads();
    }
}

__global__ void scatter_kernel(const int* __restrict__ edst, int* __restrict__ cursor,
                               int* __restrict__ perm) {
    int e = blockIdx.x * 256 + threadIdx.x;
    int d = edst[e];
    int pos = atomicAdd(&cursor[d], 1);
    perm[pos] = e;
}

// ---------------- per-node aggregation: h0[:, 512:] = sum w_e * x_bf16[src] ----------------
__global__ void aggregate_kernel(ushort_t* __restrict__ h0,
                                 const float* __restrict__ ew,
                                 const int* __restrict__ esrc,
                                 const int* __restrict__ offsets,
                                 const int* __restrict__ perm) {
    __shared__ int se[128];
    __shared__ float swt[128];
    int n = blockIdx.x;
    int tid = threadIdx.x;  // 128 threads, 4 dims each
    int beg = offsets[n], end = offsets[n + 1];
    float a0 = 0.f, a1 = 0.f, a2 = 0.f, a3 = 0.f;
    for (int base = beg; base < end; base += 128) {
        int cnt = end - base; if (cnt > 128) cnt = 128;
        if (tid < cnt) {
            int e = perm[base + tid];
            se[tid] = esrc[e];
            swt[tid] = ew[e];
        }
        __syncthreads();
        for (int j = 0; j < cnt; j++) {
            int s = se[j];
            float w = swt[j];
            ushort4 v = *(const ushort4*)&h0[(size_t)s * 1024 + tid * 4];
            a0 += w * bf2f(v.x);
            a1 += w * bf2f(v.y);
            a2 += w * bf2f(v.z);
            a3 += w * bf2f(v.w);
        }
        __syncthreads();
    }
    ushort4 o;
    o.x = f2bf(a0); o.y = f2bf(a1); o.z = f2bf(a2); o.w = f2bf(a3);
    *(ushort4*)&h0[(size_t)n * 1024 + 512 + tid * 4] = o;
}

// ---------------- bf16 MFMA GEMM: C(MxN) = A(MxK) * Bt(NxK)^T, + bias, opt ReLU ----------------
// m97 structure: 128x128 tile, BK=32, 4 waves (each 64x64 = 4x4 MFMA 16x16x32),
// global_load_lds width=16 staging, 2-barrier K-loop.
template <int K, int NOUT, bool RELU, bool OUTBF16>
__launch_bounds__(256)
__global__ void gemm_bt(const ushort_t* __restrict__ A, const ushort_t* __restrict__ B,
                        const float* __restrict__ bias, void* __restrict__ C, int Mvalid) {
    __shared__ __align__(16) ushort_t As[128 * 32];
    __shared__ __align__(16) ushort_t Bs[128 * 32];
    int tid = threadIdx.x;
    int wid = tid >> 6, lane = tid & 63;
    int m0 = blockIdx.y * 128, n0 = blockIdx.x * 128;
    int wm = (wid >> 1) * 64, wn = (wid & 1) * 64;
    int lrow = lane & 15, lq = lane >> 4;

    f32x4 acc[4][4] = {};

#pragma unroll 1
    for (int k0 = 0; k0 < K; k0 += 32) {
#pragma unroll
        for (int j = 0; j < 2; j++) {
            int cb = wid * 128 + j * 64;          // wave-uniform chunk base (16B chunks)
            int ch = cb + lane;
            int row = ch >> 2, kc = ch & 3;
            const ushort_t* ga = A + (size_t)(m0 + row) * K + k0 + kc * 8;
            __builtin_amdgcn_global_load_lds(
                (const __attribute__((address_space(1))) void*)ga,
                (__attribute__((address_space(3))) void*)(As + (size_t)cb * 8), 16, 0, 0);
            const ushort_t* gb = B + (size_t)(n0 + row) * K + k0 + kc * 8;
            __builtin_amdgcn_global_load_lds(
                (const __attribute__((address_space(1))) void*)gb,
                (__attribute__((address_space(3))) void*)(Bs + (size_t)cb * 8), 16, 0, 0);
        }
        __syncthreads();

        sh8 af[4], bfr[4];
#pragma unroll
        for (int mm = 0; mm < 4; mm++)
            af[mm] = *(const sh8*)&As[(wm + mm * 16 + lrow) * 32 + lq * 8];
#pragma unroll
        for (int nn = 0; nn < 4; nn++)
            bfr[nn] = *(const sh8*)&Bs[(wn + nn * 16 + lrow) * 32 + lq * 8];
#pragma unroll
        for (int mm = 0; mm < 4; mm++)
#pragma unroll
            for (int nn = 0; nn < 4; nn++)
                acc[mm][nn] = __builtin_amdgcn_mfma_f32_16x16x32_bf16(
                    af[mm], bfr[nn], acc[mm][nn], 0, 0, 0);
        __syncthreads();
    }

    // epilogue: C/D layout col=lane&15, row=(lane>>4)*4+reg
#pragma unroll
    for (int nn = 0; nn < 4; nn++) {
        int gn = n0 + wn + nn * 16 + lrow;
        float bv = bias[gn];
#pragma unroll
        for (int mm = 0; mm < 4; mm++) {
#pragma unroll
            for (int r = 0; r < 4; r++) {
                int gm = m0 + wm + mm * 16 + lq * 4 + r;
                float v = acc[mm][nn][r] + bv;
                if (RELU) v = v > 0.f ? v : 0.f;
                if (OUTBF16) {
                    ((ushort_t*)C)[(size_t)gm * NOUT + gn] = f2bf(v);
                } else {
                    if (gm < Mvalid) ((float*)C)[(size_t)gm * NOUT + gn] = v;
                }
            }
        }
    }
}

static inline size_t align256(size_t x) { return (x + 255) & ~(size_t)255; }

extern "C" void kernel_launch(void* const* d_in, const int* in_sizes, int n_in,
                              void* d_out, int out_size, void* d_ws, size_t ws_size,
                              hipStream_t stream) {
    const float* x   = (const float*)d_in[0];
    const float* ew  = (const float*)d_in[1];
    const float* W1  = (const float*)d_in[2];
    const float* b1  = (const float*)d_in[3];
    const float* W2  = (const float*)d_in[4];
    const float* b2  = (const float*)d_in[5];
    const float* W3  = (const float*)d_in[6];
    const float* b3  = (const float*)d_in[7];
    const int* esrc  = (const int*)d_in[8];
    const int* edst  = (const int*)d_in[9];
    float* out = (float*)d_out;

    // Workspace layout (~168.5 MB total):
    //   h0   : M_PAD x 1024 bf16            102.5 MB   (x | agg, GEMM1 input)
    //   w1t  : 2048 x 1024 bf16               4.0 MB
    //   w2t  : 2048 x 2048 bf16               8.4 MB
    //   w3t  :  512 x 2048 bf16               2.1 MB
    //   h1c  : CHUNK_M x 2048 bf16           25.7 MB   (per-chunk act; CSR aliased here)
    //   h2c  : CHUNK_M x 2048 bf16           25.7 MB
    char* ws = (char*)d_ws;
    size_t off = 0;
    ushort_t* h0  = (ushort_t*)(ws + off); off = align256(off + (size_t)M_PAD * 1024 * 2);
    ushort_t* w1t = (ushort_t*)(ws + off); off = align256(off + (size_t)H1 * K1 * 2);
    ushort_t* w2t = (ushort_t*)(ws + off); off = align256(off + (size_t)H2 * H1 * 2);
    ushort_t* w3t = (ushort_t*)(ws + off); off = align256(off + (size_t)OUT_DIM * H2 * 2);
    ushort_t* h1c = (ushort_t*)(ws + off); off = align256(off + (size_t)CHUNK_M * H1 * 2);
    ushort_t* h2c = (ushort_t*)(ws + off); off = align256(off + (size_t)CHUNK_M * H2 * 2);

    // CSR arrays aliased into h1c/h2c region (dead before first GEMM runs)
    size_t coff = (size_t)((char*)h1c - ws);
    int* counts   = (int*)(ws + coff); coff = align256(coff + (size_t)NNODES * 4);
    int* offsets  = (int*)(ws + coff); coff = align256(coff + (size_t)(NNODES + 1) * 4);
    int* cursor   = (int*)(ws + coff); coff = align256(coff + (size_t)NNODES * 4);
    int* perm     = (int*)(ws + coff); coff = align256(coff + (size_t)NEDGES * 4);

    // counts = 0
    zero_kernel<<<(NNODES + 255) / 256, 256, 0, stream>>>(counts, NNODES);

    // x -> bf16 h0[:, :512]
    convert_x_kernel<<<25000, 256, 0, stream>>>(x, h0);

    // weight transposes (fp32 KxN -> bf16 NxK)
    wtrans_kernel<<<dim3(H1 / 32, K1 / 32), dim3(32, 8), 0, stream>>>(W1, w1t, K1, H1);
    wtrans_kernel<<<dim3(H2 / 32, H1 / 32), dim3(32, 8), 0, stream>>>(W2, w2t, H1, H2);
    wtrans_kernel<<<dim3(OUT_DIM / 32, H2 / 32), dim3(32, 8), 0, stream>>>(W3, w3t, H2, OUT_DIM);

    // CSR by dst
    hist_kernel<<<NEDGES / 256, 256, 0, stream>>>(edst, counts);
    scan_kernel<<<1, 1024, 0, stream>>>(counts, offsets, cursor, NNODES);
    scatter_kernel<<<NEDGES / 256, 256, 0, stream>>>(edst, cursor, perm);

    // aggregate into h0[:, 512:]
    aggregate_kernel<<<NNODES, 128, 0, stream>>>(h0, ew, esrc, offsets, perm);

    // MLP in M-chunks of CHUNK_TILES row-tiles
    for (int t0 = 0; t0 < TOTAL_TILES; t0 += CHUNK_TILES) {
        int tiles = TOTAL_TILES - t0; if (tiles > CHUNK_TILES) tiles = CHUNK_TILES;
        int row0 = t0 * 128;
        gemm_bt<K1, H1, true, true><<<dim3(H1 / 128, tiles), 256, 0, stream>>>(
            h0 + (size_t)row0 * K1, w1t, b1, h1c, tiles * 128);
        gemm_bt<H1, H2, true, true><<<dim3(H2 / 128, tiles), 256, 0, stream>>>(
            h1c, w2t, b2, h2c, tiles * 128);
        gemm_bt<H2, OUT_DIM, false, false><<<dim3(OUT_DIM / 128, tiles), 256, 0, stream>>>(
            h2c, w3t, b3, out + (size_t)row0 * OUT_DIM, NNODES - row0);
    }
}

// Round 3
// 2037.876 us; speedup vs baseline: 1.1922x; 1.1922x over previous
//
#include <hip/hip_runtime.h>

#define NNODES 50000
#define NEDGES 1600000
#define IN_DIM 512
#define K1 1024
#define H1 2048
#define H2 2048
#define OUT_DIM 512
#define M_PAD 50048        // 391 * 128
#define TOTAL_TILES 391
#define SCAN_BLOCKS 49     // ceil(50000 / 1024)

typedef unsigned short ushort_t;
typedef short sh8 __attribute__((ext_vector_type(8)));
typedef float f32x4 __attribute__((ext_vector_type(4)));

__device__ __forceinline__ ushort_t f2bf(float f) {
    unsigned u = __float_as_uint(f);
    unsigned r = (u + 0x7FFFu + ((u >> 16) & 1u)) >> 16;
    return (ushort_t)r;
}
__device__ __forceinline__ float bf2f(ushort_t h) {
    return __uint_as_float(((unsigned)h) << 16);
}

// ---------------- zero fill ----------------
__global__ void zero_kernel(int* __restrict__ p, int n) {
    int i = blockIdx.x * 256 + threadIdx.x;
    if (i < n) p[i] = 0;
}

// ---------------- x -> bf16 into h0[:, :512] ----------------
__global__ void convert_x_kernel(const float* __restrict__ x, ushort_t* __restrict__ h0) {
    int t = blockIdx.x * 256 + threadIdx.x;      // 50000*128 threads
    int n = t >> 7, c = t & 127;
    float4 v = ((const float4*)x)[n * 128 + c];
    ushort4 o;
    o.x = f2bf(v.x); o.y = f2bf(v.y); o.z = f2bf(v.z); o.w = f2bf(v.w);
    ((ushort4*)h0)[n * 256 + c] = o;
}

// ---------------- W (K x N fp32) -> Wt (N x K bf16) ----------------
__global__ void wtrans_kernel(const float* __restrict__ W, ushort_t* __restrict__ Wt,
                              int K, int Nn) {
    __shared__ float t[32][33];
    int n0 = blockIdx.x * 32, k0 = blockIdx.y * 32;
    int tx = threadIdx.x, ty = threadIdx.y;  // 32 x 8
#pragma unroll
    for (int i = 0; i < 4; i++)
        t[ty + 8 * i][tx] = W[(size_t)(k0 + ty + 8 * i) * Nn + n0 + tx];
    __syncthreads();
#pragma unroll
    for (int i = 0; i < 4; i++)
        Wt[(size_t)(n0 + ty + 8 * i) * K + k0 + tx] = f2bf(t[tx][ty + 8 * i]);
}

// ---------------- CSR build ----------------
__global__ void hist_kernel(const int* __restrict__ edst, int* __restrict__ counts) {
    int e = blockIdx.x * 256 + threadIdx.x;
    atomicAdd(&counts[edst[e]], 1);
}

// Hierarchical scan: (A) per-block inclusive scan, (B) serial carry scan, (C) finalize.
__global__ void scan_blocks_kernel(const int* __restrict__ counts, int* __restrict__ incl,
                                   int* __restrict__ block_sums) {
    __shared__ int s[1024];
    int b = blockIdx.x, tid = threadIdx.x;
    int i = b * 1024 + tid;
    int c = (i < NNODES) ? counts[i] : 0;
    s[tid] = c;
    __syncthreads();
    for (int off = 1; off < 1024; off <<= 1) {
        int v = (tid >= off) ? s[tid - off] : 0;
        __syncthreads();
        s[tid] += v;
        __syncthreads();
    }
    if (i < NNODES) incl[i] = s[tid];
    if (tid == 1023) block_sums[b] = s[1023];
}

__global__ void scan_sums_kernel(const int* __restrict__ block_sums, int* __restrict__ carry) {
    if (threadIdx.x == 0 && blockIdx.x == 0) {
        int run = 0;
        for (int b = 0; b < SCAN_BLOCKS; b++) { carry[b] = run; run += block_sums[b]; }
    }
}

__global__ void scan_finalize_kernel(const int* __restrict__ counts, const int* __restrict__ incl,
                                     const int* __restrict__ carry, int* __restrict__ offsets,
                                     int* __restrict__ cursor) {
    int b = blockIdx.x, tid = threadIdx.x;
    int i = b * 1024 + tid;
    if (i < NNODES) {
        int v = incl[i] + carry[b];
        offsets[i + 1] = v;
        cursor[i] = v - counts[i];
    }
    if (i == 0) offsets[0] = 0;
}

__global__ void scatter_kernel(const int* __restrict__ edst, int* __restrict__ cursor,
                               int* __restrict__ perm) {
    int e = blockIdx.x * 256 + threadIdx.x;
    int d = edst[e];
    int pos = atomicAdd(&cursor[d], 1);
    perm[pos] = e;
}

// ---------------- per-node aggregation: h0[:, 512:] = sum w_e * x_bf16[src] ----------------
__global__ void aggregate_kernel(ushort_t* __restrict__ h0,
                                 const float* __restrict__ ew,
                                 const int* __restrict__ esrc,
                                 const int* __restrict__ offsets,
                                 const int* __restrict__ perm) {
    __shared__ int se[128];
    __shared__ float swt[128];
    int n = blockIdx.x;
    int tid = threadIdx.x;  // 128 threads, 4 dims each
    int beg = offsets[n], end = offsets[n + 1];
    float a0 = 0.f, a1 = 0.f, a2 = 0.f, a3 = 0.f;
    for (int base = beg; base < end; base += 128) {
        int cnt = end - base; if (cnt > 128) cnt = 128;
        if (tid < cnt) {
            int e = perm[base + tid];
            se[tid] = esrc[e];
            swt[tid] = ew[e];
        }
        __syncthreads();
        for (int j = 0; j < cnt; j++) {
            int s = se[j];
            float w = swt[j];
            ushort4 v = *(const ushort4*)&h0[(size_t)s * 1024 + tid * 4];
            a0 += w * bf2f(v.x);
            a1 += w * bf2f(v.y);
            a2 += w * bf2f(v.z);
            a3 += w * bf2f(v.w);
        }
        __syncthreads();
    }
    ushort4 o;
    o.x = f2bf(a0); o.y = f2bf(a1); o.z = f2bf(a2); o.w = f2bf(a3);
    *(ushort4*)&h0[(size_t)n * 1024 + 512 + tid * 4] = o;
}

// ---------------- bf16 MFMA GEMM: C(MxN) = A(MxK) * Bt(NxK)^T, + bias, opt ReLU ----------------
template <int K, int NOUT, bool RELU, bool OUTBF16>
__launch_bounds__(256)
__global__ void gemm_bt(const ushort_t* __restrict__ A, const ushort_t* __restrict__ B,
                        const float* __restrict__ bias, void* __restrict__ C, int Mvalid) {
    __shared__ __align__(16) ushort_t As[128 * 32];
    __shared__ __align__(16) ushort_t Bs[128 * 32];
    int tid = threadIdx.x;
    int wid = tid >> 6, lane = tid & 63;
    int m0 = blockIdx.y * 128, n0 = blockIdx.x * 128;
    int wm = (wid >> 1) * 64, wn = (wid & 1) * 64;
    int lrow = lane & 15, lq = lane >> 4;

    f32x4 acc[4][4] = {};

#pragma unroll 1
    for (int k0 = 0; k0 < K; k0 += 32) {
#pragma unroll
        for (int j = 0; j < 2; j++) {
            int cb = wid * 128 + j * 64;          // wave-uniform chunk base (16B chunks)
            int ch = cb + lane;
            int row = ch >> 2, kc = ch & 3;
            const ushort_t* ga = A + (size_t)(m0 + row) * K + k0 + kc * 8;
            __builtin_amdgcn_global_load_lds(
                (const __attribute__((address_space(1))) void*)ga,
                (__attribute__((address_space(3))) void*)(As + (size_t)cb * 8), 16, 0, 0);
            const ushort_t* gb = B + (size_t)(n0 + row) * K + k0 + kc * 8;
            __builtin_amdgcn_global_load_lds(
                (const __attribute__((address_space(1))) void*)gb,
                (__attribute__((address_space(3))) void*)(Bs + (size_t)cb * 8), 16, 0, 0);
        }
        __syncthreads();

        sh8 af[4], bfr[4];
#pragma unroll
        for (int mm = 0; mm < 4; mm++)
            af[mm] = *(const sh8*)&As[(wm + mm * 16 + lrow) * 32 + lq * 8];
#pragma unroll
        for (int nn = 0; nn < 4; nn++)
            bfr[nn] = *(const sh8*)&Bs[(wn + nn * 16 + lrow) * 32 + lq * 8];
#pragma unroll
        for (int mm = 0; mm < 4; mm++)
#pragma unroll
            for (int nn = 0; nn < 4; nn++)
                acc[mm][nn] = __builtin_amdgcn_mfma_f32_16x16x32_bf16(
                    af[mm], bfr[nn], acc[mm][nn], 0, 0, 0);
        __syncthreads();
    }

    // epilogue: C/D layout col=lane&15, row=(lane>>4)*4+reg
#pragma unroll
    for (int nn = 0; nn < 4; nn++) {
        int gn = n0 + wn + nn * 16 + lrow;
        float bv = bias[gn];
#pragma unroll
        for (int mm = 0; mm < 4; mm++) {
#pragma unroll
            for (int r = 0; r < 4; r++) {
                int gm = m0 + wm + mm * 16 + lq * 4 + r;
                float v = acc[mm][nn][r] + bv;
                if (RELU) v = v > 0.f ? v : 0.f;
                if (OUTBF16) {
                    ((ushort_t*)C)[(size_t)gm * NOUT + gn] = f2bf(v);
                } else {
                    if (gm < Mvalid) ((float*)C)[(size_t)gm * NOUT + gn] = v;
                }
            }
        }
    }
}

static inline size_t align256(size_t x) { return (x + 255) & ~(size_t)255; }

extern "C" void kernel_launch(void* const* d_in, const int* in_sizes, int n_in,
                              void* d_out, int out_size, void* d_ws, size_t ws_size,
                              hipStream_t stream) {
    const float* x   = (const float*)d_in[0];
    const float* ew  = (const float*)d_in[1];
    const float* W1  = (const float*)d_in[2];
    const float* b1  = (const float*)d_in[3];
    const float* W2  = (const float*)d_in[4];
    const float* b2  = (const float*)d_in[5];
    const float* W3  = (const float*)d_in[6];
    const float* b3  = (const float*)d_in[7];
    const int* esrc  = (const int*)d_in[8];
    const int* edst  = (const int*)d_in[9];
    float* out = (float*)d_out;

    // Fixed workspace: h0 (102.5 MB) + bf16 weights (14.5 MB).
    // Chunk area (rest of ws): h1c + h2c, dynamically sized from ws_size.
    // CSR arrays (7 MB) aliased at the start of the chunk area (dead before GEMM1).
    char* ws = (char*)d_ws;
    size_t off = 0;
    ushort_t* h0  = (ushort_t*)(ws + off); off = align256(off + (size_t)M_PAD * 1024 * 2);
    ushort_t* w1t = (ushort_t*)(ws + off); off = align256(off + (size_t)H1 * K1 * 2);
    ushort_t* w2t = (ushort_t*)(ws + off); off = align256(off + (size_t)H2 * H1 * 2);
    ushort_t* w3t = (ushort_t*)(ws + off); off = align256(off + (size_t)OUT_DIM * H2 * 2);
    size_t fixed_end = off;

    // Dynamic chunk tiles: each tile needs 128*2048*2 bytes in each of h1c/h2c.
    const size_t per_tile = (size_t)128 * 2048 * 2 * 2;  // 1 MiB
    size_t avail = (ws_size > fixed_end + 512) ? (ws_size - fixed_end - 512) : 0;
    int T = (int)(avail / per_tile);
    if (T > TOTAL_TILES) T = TOTAL_TILES;
    if (T < 8) T = 8;  // ws_size >= 168.5 MB (verified R2) => T >= 51; this is a floor only
    int nchunks = (TOTAL_TILES + T - 1) / T;
    T = (TOTAL_TILES + nchunks - 1) / nchunks;  // balance chunk sizes

    ushort_t* h1c = (ushort_t*)(ws + fixed_end);
    ushort_t* h2c = (ushort_t*)(ws + fixed_end + (size_t)T * 128 * 2048 * 2);

    // CSR arrays aliased into chunk area (used only before the first GEMM)
    size_t coff = fixed_end;
    int* counts     = (int*)(ws + coff); coff = align256(coff + (size_t)NNODES * 4);
    int* offsets    = (int*)(ws + coff); coff = align256(coff + (size_t)(NNODES + 1) * 4);
    int* cursor     = (int*)(ws + coff); coff = align256(coff + (size_t)NNODES * 4);
    int* incl       = (int*)(ws + coff); coff = align256(coff + (size_t)NNODES * 4);
    int* perm       = (int*)(ws + coff); coff = align256(coff + (size_t)NEDGES * 4);
    int* block_sums = (int*)(ws + coff); coff = align256(coff + (size_t)SCAN_BLOCKS * 4);
    int* carry      = (int*)(ws + coff); coff = align256(coff + (size_t)SCAN_BLOCKS * 4);

    // counts = 0
    zero_kernel<<<(NNODES + 255) / 256, 256, 0, stream>>>(counts, NNODES);

    // x -> bf16 h0[:, :512]
    convert_x_kernel<<<25000, 256, 0, stream>>>(x, h0);

    // weight transposes (fp32 KxN -> bf16 NxK)
    wtrans_kernel<<<dim3(H1 / 32, K1 / 32), dim3(32, 8), 0, stream>>>(W1, w1t, K1, H1);
    wtrans_kernel<<<dim3(H2 / 32, H1 / 32), dim3(32, 8), 0, stream>>>(W2, w2t, H1, H2);
    wtrans_kernel<<<dim3(OUT_DIM / 32, H2 / 32), dim3(32, 8), 0, stream>>>(W3, w3t, H2, OUT_DIM);

    // CSR by dst (hierarchical scan)
    hist_kernel<<<NEDGES / 256, 256, 0, stream>>>(edst, counts);
    scan_blocks_kernel<<<SCAN_BLOCKS, 1024, 0, stream>>>(counts, incl, block_sums);
    scan_sums_kernel<<<1, 64, 0, stream>>>(block_sums, carry);
    scan_finalize_kernel<<<SCAN_BLOCKS, 1024, 0, stream>>>(counts, incl, carry, offsets, cursor);
    scatter_kernel<<<NEDGES / 256, 256, 0, stream>>>(edst, cursor, perm);

    // aggregate into h0[:, 512:]
    aggregate_kernel<<<NNODES, 128, 0, stream>>>(h0, ew, esrc, offsets, perm);

    // MLP in M-chunks of T row-tiles
    for (int t0 = 0; t0 < TOTAL_TILES; t0 += T) {
        int tiles = TOTAL_TILES - t0; if (tiles > T) tiles = T;
        int row0 = t0 * 128;
        gemm_bt<K1, H1, true, true><<<dim3(H1 / 128, tiles), 256, 0, stream>>>(
            h0 + (size_t)row0 * K1, w1t, b1, h1c, tiles * 128);
        gemm_bt<H1, H2, true, true><<<dim3(H2 / 128, tiles), 256, 0, stream>>>(
            h1c, w2t, b2, h2c, tiles * 128);
        gemm_bt<H2, OUT_DIM, false, false><<<dim3(OUT_DIM / 128, tiles), 256, 0, stream>>>(
            h2c, w3t, b3, out + (size_t)row0 * OUT_DIM, NNODES - row0);
    }
}